// Round 1
// baseline (1659.198 us; speedup 1.0000x reference)
//
#include <hip/hip_runtime.h>
#include <stdint.h>

typedef float f32x4 __attribute__((ext_vector_type(4)));
typedef short s16x8 __attribute__((ext_vector_type(8)));
typedef __attribute__((address_space(1))) void gvoid_t;
typedef __attribute__((address_space(3))) void svoid_t;

static __device__ __forceinline__ unsigned short f2bf(float f) {
  uint32_t u = __builtin_bit_cast(uint32_t, f);
  return (unsigned short)((u + 0x7fffu + ((u >> 16) & 1u)) >> 16);
}

// ---------------- phase 0: Wo fp32 -> bf16 ----------------
__global__ void wo_to_bf16(const float* __restrict__ src,
                           unsigned short* __restrict__ dst, int n) {
  int i = blockIdx.x * 256 + threadIdx.x;
  if (i < n) dst[i] = f2bf(src[i]);
}

// ---------------- phase 1: attention mixer (fp32), writes bf16 A ----------------
// one wave per b; lane = output channel e for q/k; Wq/Wk rows in registers.
__global__ __launch_bounds__(256) void attn_mix(
    const float* __restrict__ x, const float* __restrict__ v,
    const float* __restrict__ Wq, const float* __restrict__ bq,
    const float* __restrict__ Wk, const float* __restrict__ bk,
    unsigned short* __restrict__ Aout, int B) {
  __shared__ float xs_all[4][1024];     // x[b] 16x64
  __shared__ float qs_all[4][16 * 68];  // q (padded rows, 16B aligned); reused as vs
  __shared__ float ks_all[4][16 * 68];  // k
  __shared__ float at_all[4][256];      // attn transposed [g][h]

  const int tid = threadIdx.x;
  const int wave = tid >> 6;
  const int lane = tid & 63;

  float* xs = xs_all[wave];
  float* qs = qs_all[wave];
  float* ks = ks_all[wave];
  float* vs = qs_all[wave];  // reuse after dist consumed q
  float* attnT = at_all[wave];

  // per-lane weight rows (e = lane): wq[d] = Wq[lane][d]
  float wq[64], wk[64];
  {
    const float4* Wq4 = (const float4*)Wq;
    const float4* Wk4 = (const float4*)Wk;
#pragma unroll
    for (int d4 = 0; d4 < 16; ++d4) {
      float4 a = Wq4[lane * 16 + d4];
      wq[4 * d4 + 0] = a.x; wq[4 * d4 + 1] = a.y;
      wq[4 * d4 + 2] = a.z; wq[4 * d4 + 3] = a.w;
      float4 c = Wk4[lane * 16 + d4];
      wk[4 * d4 + 0] = c.x; wk[4 * d4 + 1] = c.y;
      wk[4 * d4 + 2] = c.z; wk[4 * d4 + 3] = c.w;
    }
  }
  const float bql = bq[lane];
  const float bkl = bk[lane];

  const int g = lane & 15;
  const int quad = lane >> 4;

  const int b0 = blockIdx.x * 16 + wave * 4;
#pragma unroll 1
  for (int bi = 0; bi < 4; ++bi) {
    const int b = b0 + bi;
    __syncthreads();  // protect prev-iter LDS reads
    {
      const float4* xb = (const float4*)(x + (size_t)b * 1024);
      float4* xs4 = (float4*)xs;
#pragma unroll
      for (int i = 0; i < 4; ++i) xs4[i * 64 + lane] = xb[i * 64 + lane];
    }
    __syncthreads();
    // q[i][lane], k[i][lane]
#pragma unroll 4
    for (int i = 0; i < 16; ++i) {
      const float4* xr = (const float4*)xs + i * 16;
      float qa0 = bql, ka0 = bkl, qa1 = 0.f, ka1 = 0.f;
#pragma unroll
      for (int d4 = 0; d4 < 16; d4 += 2) {
        float4 xv = xr[d4];
        qa0 = fmaf(xv.x, wq[4 * d4 + 0], qa0);
        qa0 = fmaf(xv.y, wq[4 * d4 + 1], qa0);
        qa0 = fmaf(xv.z, wq[4 * d4 + 2], qa0);
        qa0 = fmaf(xv.w, wq[4 * d4 + 3], qa0);
        ka0 = fmaf(xv.x, wk[4 * d4 + 0], ka0);
        ka0 = fmaf(xv.y, wk[4 * d4 + 1], ka0);
        ka0 = fmaf(xv.z, wk[4 * d4 + 2], ka0);
        ka0 = fmaf(xv.w, wk[4 * d4 + 3], ka0);
        float4 xw = xr[d4 + 1];
        qa1 = fmaf(xw.x, wq[4 * d4 + 4], qa1);
        qa1 = fmaf(xw.y, wq[4 * d4 + 5], qa1);
        qa1 = fmaf(xw.z, wq[4 * d4 + 6], qa1);
        qa1 = fmaf(xw.w, wq[4 * d4 + 7], qa1);
        ka1 = fmaf(xw.x, wk[4 * d4 + 4], ka1);
        ka1 = fmaf(xw.y, wk[4 * d4 + 5], ka1);
        ka1 = fmaf(xw.z, wk[4 * d4 + 6], ka1);
        ka1 = fmaf(xw.w, wk[4 * d4 + 7], ka1);
      }
      qs[i * 68 + lane] = qa0 + qa1;
      ks[i * 68 + lane] = ka0 + ka1;
    }
    __syncthreads();
    // dist(h = j*4+quad, g) = |q_h - k_g|^2  (== clamped q2+k2-2qk exactly)
    float att[4];
#pragma unroll
    for (int j = 0; j < 4; ++j) {
      const int h = j * 4 + quad;
      const float4* qr = (const float4*)(qs + h * 68);
      const float4* kr = (const float4*)(ks + g * 68);
      float s0 = 0.f, s1 = 0.f;
#pragma unroll
      for (int d4 = 0; d4 < 16; d4 += 2) {
        float4 qv = qr[d4], kv = kr[d4];
        float d0 = qv.x - kv.x; s0 = fmaf(d0, d0, s0);
        float d1 = qv.y - kv.y; s0 = fmaf(d1, d1, s0);
        float d2 = qv.z - kv.z; s0 = fmaf(d2, d2, s0);
        float d3 = qv.w - kv.w; s0 = fmaf(d3, d3, s0);
        float4 qw = qr[d4 + 1], kw = kr[d4 + 1];
        float e0 = qw.x - kw.x; s1 = fmaf(e0, e0, s1);
        float e1 = qw.y - kw.y; s1 = fmaf(e1, e1, s1);
        float e2 = qw.z - kw.z; s1 = fmaf(e2, e2, s1);
        float e3 = qw.w - kw.w; s1 = fmaf(e3, e3, s1);
      }
      att[j] = s0 + s1;
    }
    __syncthreads();  // q/k reads done; vs may overwrite qs region
    // softmax over g within each 16-lane group (row h)
#pragma unroll
    for (int j = 0; j < 4; ++j) {
      float mn = att[j];
#pragma unroll
      for (int m = 8; m >= 1; m >>= 1) mn = fminf(mn, __shfl_xor(mn, m, 16));
      float e = __expf(mn - att[j]);
      float sum = e;
#pragma unroll
      for (int m = 8; m >= 1; m >>= 1) sum += __shfl_xor(sum, m, 16);
      attnT[g * 16 + j * 4 + quad] = e / sum;  // attnT[g][h]
    }
    {
      const float4* vb = (const float4*)(v + (size_t)b * 1024);
      float4* vs4 = (float4*)vs;
#pragma unroll
      for (int i = 0; i < 4; ++i) vs4[i * 64 + lane] = vb[i * 64 + lane];
    }
    __syncthreads();
    // mixed[h][lane] = sum_g attn[h][g] * {x,v}[g][lane]
    float xm[16], vm[16];
#pragma unroll
    for (int i = 0; i < 16; ++i) { xm[i] = 0.f; vm[i] = 0.f; }
#pragma unroll 4
    for (int gg = 0; gg < 16; ++gg) {
      float xv = xs[gg * 64 + lane];
      float vv = vs[gg * 64 + lane];
      const float4* ar = (const float4*)(attnT + gg * 16);
#pragma unroll
      for (int c4 = 0; c4 < 4; ++c4) {
        float4 a = ar[c4];
        xm[c4 * 4 + 0] = fmaf(a.x, xv, xm[c4 * 4 + 0]);
        xm[c4 * 4 + 1] = fmaf(a.y, xv, xm[c4 * 4 + 1]);
        xm[c4 * 4 + 2] = fmaf(a.z, xv, xm[c4 * 4 + 2]);
        xm[c4 * 4 + 3] = fmaf(a.w, xv, xm[c4 * 4 + 3]);
        vm[c4 * 4 + 0] = fmaf(a.x, vv, vm[c4 * 4 + 0]);
        vm[c4 * 4 + 1] = fmaf(a.y, vv, vm[c4 * 4 + 1]);
        vm[c4 * 4 + 2] = fmaf(a.z, vv, vm[c4 * 4 + 2]);
        vm[c4 * 4 + 3] = fmaf(a.w, vv, vm[c4 * 4 + 3]);
      }
    }
    unsigned short* ox = Aout + (size_t)b * 1024 + lane;
    unsigned short* ov = Aout + (size_t)(B + b) * 1024 + lane;
#pragma unroll
    for (int i = 0; i < 16; ++i) {
      ox[i * 64] = f2bf(xm[i]);
      ov[i * 64] = f2bf(vm[i]);
    }
  }
}

// ---------------- phase 2: C[M,1024] = A[M,1024] @ Wo^T + bo (bf16 MFMA) ----------------
// m97 structure: 128x128 tile, BK=32, 4 waves 2x2, global_load_lds width 16.
__global__ __launch_bounds__(256) void gemm_bt(
    const unsigned short* __restrict__ A,   // [M][1024] bf16
    const unsigned short* __restrict__ Bw,  // [1024][1024] bf16 (Wo, row = n)
    const float* __restrict__ bias,         // [1024]
    float* __restrict__ C, int M) {
  __shared__ unsigned short As[128 * 32];
  __shared__ unsigned short Bs[128 * 32];

  const int tid = threadIdx.x;
  const int lane = tid & 63;
  const int wave = tid >> 6;
  const int wm = wave >> 1;
  const int wn = wave & 1;
  const int m0 = blockIdx.y * 128;
  const int n0 = blockIdx.x * 128;

  f32x4 acc[4][4];
#pragma unroll
  for (int i = 0; i < 4; ++i)
#pragma unroll
    for (int j = 0; j < 4; ++j) acc[i][j] = (f32x4)(0.f);

  const int row16 = lane & 15;
  const int q8 = (lane >> 4) * 8;  // k-offset within tile for A/B frags

  for (int k0 = 0; k0 < 1024; k0 += 32) {
    __syncthreads();  // prev-iter frag reads done before restage
#pragma unroll
    for (int it = 0; it < 2; ++it) {
      int c = it * 256 + tid;  // chunk 0..511; per-wave lane-contiguous
      int r = c >> 2;
      int ce = (c & 3) * 8;
      const unsigned short* gA = A + (size_t)(m0 + r) * 1024 + k0 + ce;
      const unsigned short* gB = Bw + (size_t)(n0 + r) * 1024 + k0 + ce;
      __builtin_amdgcn_global_load_lds((gvoid_t*)gA, (svoid_t*)(As + c * 8), 16, 0, 0);
      __builtin_amdgcn_global_load_lds((gvoid_t*)gB, (svoid_t*)(Bs + c * 8), 16, 0, 0);
    }
    __syncthreads();  // drains vmcnt(0) per barrier semantics

    s16x8 af[4], bfr[4];
#pragma unroll
    for (int i = 0; i < 4; ++i)
      af[i] = *(const s16x8*)(As + (wm * 64 + i * 16 + row16) * 32 + q8);
#pragma unroll
    for (int j = 0; j < 4; ++j)
      bfr[j] = *(const s16x8*)(Bs + (wn * 64 + j * 16 + row16) * 32 + q8);
#pragma unroll
    for (int i = 0; i < 4; ++i)
#pragma unroll
      for (int j = 0; j < 4; ++j)
        acc[i][j] = __builtin_amdgcn_mfma_f32_16x16x32_bf16(af[i], bfr[j], acc[i][j], 0, 0, 0);
  }

  // epilogue: C/D layout col = lane&15, row = (lane>>4)*4 + reg
  const int col = lane & 15;
  const int qrow = (lane >> 4) * 4;
#pragma unroll
  for (int j = 0; j < 4; ++j) {
    const int n = n0 + wn * 64 + j * 16 + col;
    const float bv = bias[n];
#pragma unroll
    for (int i = 0; i < 4; ++i) {
      const int mbase = m0 + wm * 64 + i * 16 + qrow;
#pragma unroll
      for (int r = 0; r < 4; ++r) {
        C[(size_t)(mbase + r) * 1024 + n] = acc[i][j][r] + bv;
      }
    }
  }
}

extern "C" void kernel_launch(void* const* d_in, const int* in_sizes, int n_in,
                              void* d_out, int out_size, void* d_ws, size_t ws_size,
                              hipStream_t stream) {
  const float* x  = (const float*)d_in[0];
  const float* v  = (const float*)d_in[1];
  const float* Wq = (const float*)d_in[2];
  const float* bq = (const float*)d_in[3];
  const float* Wk = (const float*)d_in[4];
  const float* bk = (const float*)d_in[5];
  const float* Wo = (const float*)d_in[6];
  const float* bo = (const float*)d_in[7];
  float* out = (float*)d_out;

  const int B = in_sizes[0] / 1024;  // 32768
  const int M = 2 * B;               // 65536: rows 0..B-1 = x_mixed, B..2B-1 = v_mixed

  unsigned short* Abf  = (unsigned short*)d_ws;                      // M*1024 bf16
  unsigned short* WoBf = (unsigned short*)d_ws + (size_t)M * 1024;   // 1024*1024 bf16

  hipLaunchKernelGGL(wo_to_bf16, dim3(4096), dim3(256), 0, stream,
                     Wo, WoBf, 1024 * 1024);
  hipLaunchKernelGGL(attn_mix, dim3(B / 16), dim3(256), 0, stream,
                     x, v, Wq, bq, Wk, bk, Abf, B);
  hipLaunchKernelGGL(gemm_bt, dim3(8, M / 128), dim3(256), 0, stream,
                     Abf, WoBf, bo, out, M);
}